// Round 11
// baseline (251.947 us; speedup 1.0000x reference)
//
#include <hip/hip_runtime.h>
#include <hip/hip_bf16.h>
#include <cmath>

#define B_    16
#define L_    2048
#define T_    32768   // B_*L_
#define DM_   128
#define DI_   256
#define DXBC_ 384
#define DS_   64
#define HD_   64
#define NH_   4
#define NC_   32      // chunks per sequence (L_/64)

typedef __hip_bfloat16 bf16;
typedef __attribute__((ext_vector_type(8))) short short8;
typedef __attribute__((ext_vector_type(4))) float f32x4;

__device__ __forceinline__ float b2f(bf16 v) { return __bfloat162float(v); }
__device__ __forceinline__ bf16  f2b(float f) { return __float2bfloat16(f); }
__device__ __forceinline__ short f2bs(float f) { bf16 h = __float2bfloat16(f); return *reinterpret_cast<short*>(&h); }
__device__ __forceinline__ float bs2f(short s) { bf16 h = *reinterpret_cast<bf16*>(&s); return __bfloat162float(h); }
__device__ __forceinline__ short bbits(bf16 v) { return *reinterpret_cast<short*>(&v); }
// fast transcendentals: v_exp_f32 / v_log_f32 / v_rcp_f32 (1-2 ulp, fine for bf16)
__device__ __forceinline__ float frcp_(float x) { return __builtin_amdgcn_rcpf(x); }
__device__ __forceinline__ float sigmoidf_(float x) { return frcp_(1.f + __expf(-x)); }
__device__ __forceinline__ float softplusf_(float x) { return (x > 20.f) ? x : __logf(1.f + __expf(x)); }
__device__ __forceinline__ float expneg_(float x) { return __expf(fminf(x, 0.f)); }

struct __align__(8) S4 { short a, b, c, d; };

#define NWI 82432   // 644*128
#define NWO 32768   // 128*256

// ---------------------------------------------------------------------------
// K0: one-time f32 -> bf16 conversion of Wi_f/b, Wo_f/b (weights only).
// ---------------------------------------------------------------------------
__global__ __launch_bounds__(256) void k_prep(
    const float* __restrict__ WiF, const float* __restrict__ WiB,
    const float* __restrict__ WoF, const float* __restrict__ WoB,
    bf16* __restrict__ WiFb, bf16* __restrict__ WiBb,
    bf16* __restrict__ WoFb, bf16* __restrict__ WoBb)
{
    const int gid = blockIdx.x * 256 + threadIdx.x;
    const int stride = gridDim.x * 256;
    for (int i = gid; i < NWI / 4; i += stride) {
        float4 v = ((const float4*)WiF)[i];
        S4 s = { f2bs(v.x), f2bs(v.y), f2bs(v.z), f2bs(v.w) };
        ((S4*)WiFb)[i] = s;
        v = ((const float4*)WiB)[i];
        S4 t = { f2bs(v.x), f2bs(v.y), f2bs(v.z), f2bs(v.w) };
        ((S4*)WiBb)[i] = t;
    }
    for (int i = gid; i < NWO / 4; i += stride) {
        float4 v = ((const float4*)WoF)[i];
        S4 s = { f2bs(v.x), f2bs(v.y), f2bs(v.z), f2bs(v.w) };
        ((S4*)WoFb)[i] = s;
        v = ((const float4*)WoB)[i];
        S4 t = { f2bs(v.x), f2bs(v.y), f2bs(v.z), f2bs(v.w) };
        ((S4*)WoBb)[i] = t;
    }
}

// ---------------------------------------------------------------------------
// K1 (MFMA): in_proj GEMM; x read f32 directly; weights from L2.
// Z tiles: swapped orientation, zero barriers. Conv tiles: raws round-trip,
// next-tile weight prefetch. dt: wave-0 MFMA. grid (512, 2), block 256.
// ---------------------------------------------------------------------------
__global__ __launch_bounds__(256) void k_inproj_mfma(
    const float* __restrict__ x, const bf16* __restrict__ WiFb, const bf16* __restrict__ WiBb,
    const float* __restrict__ cwF, const float* __restrict__ cbF,
    const float* __restrict__ cwB, const float* __restrict__ cbB,
    const float* __restrict__ dtbF, const float* __restrict__ dtbB,
    bf16* __restrict__ Z, bf16* __restrict__ XBC, float* __restrict__ DTV)
{
    const int tid  = threadIdx.x;
    const int wave = tid >> 6, lane = tid & 63;
    const int ln15 = lane & 15, q = lane >> 4;
    const int dir  = blockIdx.y;
    const bf16* Wi = dir ? WiBb : WiFb;
    const int t0 = blockIdx.x * 64;
    const int batch = t0 >> 11, l0 = t0 & (L_ - 1);
    const size_t rowbase = (size_t)dir * T_ + t0;

    __shared__ __align__(16) short xs[80][136];    // tokens l0-16 .. l0+63
    __shared__ __align__(16) short raws[80][80];   // conv scratch

    for (int u = tid; u < 1280; u += 256) {
        int r = u >> 4, g = u & 15;
        int l = l0 - 16 + r;
        short8 v = {0, 0, 0, 0, 0, 0, 0, 0};
        if (l >= 0) {
            int sl = dir ? (L_ - 1 - l) : l;
            const float* xp = x + ((size_t)batch * L_ + sl) * DM_ + g * 8;
            float4 a = *(const float4*)xp;
            float4 bb = *(const float4*)(xp + 4);
            v = (short8){ f2bs(a.x), f2bs(a.y), f2bs(a.z), f2bs(a.w),
                          f2bs(bb.x), f2bs(bb.y), f2bs(bb.z), f2bs(bb.w) };
        }
        *(short8*)&xs[r][g * 8] = v;
    }
    __syncthreads();

    // ---- Z tiles (4): swapped orientation, zero barriers ----
#pragma unroll
    for (int zt = 0; zt < 4; ++zt) {
        const int c0 = zt * 64;
        short8 wf[4];
#pragma unroll
        for (int ks = 0; ks < 4; ++ks)
            wf[ks] = *(const short8*)(Wi + (size_t)(c0 + 16 * wave + ln15) * DM_ + ks * 32 + q * 8);
#pragma unroll
        for (int ct = 0; ct < 4; ++ct) {
            f32x4 acc = (f32x4){0.f, 0.f, 0.f, 0.f};
#pragma unroll
            for (int ks = 0; ks < 4; ++ks) {
                short8 xf = *(const short8*)&xs[16 + 16 * ct + ln15][ks * 32 + q * 8];
                acc = __builtin_amdgcn_mfma_f32_16x16x32_bf16(wf[ks], xf, acc, 0, 0, 0);
            }
            S4 s = { f2bs(acc[0]), f2bs(acc[1]), f2bs(acc[2]), f2bs(acc[3]) };
            *(S4*)(Z + (rowbase + 16 * ct + ln15) * DI_ + c0 + 16 * wave + 4 * q) = s;
        }
    }

    // ---- conv tiles (6): raws round-trip + next-tile weight prefetch ----
    const float* cw = dir ? cwB : cwF;
    const float* cb = dir ? cbB : cbF;
    const int c4 = (tid & 15) * 4;
    short8 bcur[4];
#pragma unroll
    for (int ks = 0; ks < 4; ++ks)
        bcur[ks] = *(const short8*)(Wi + (size_t)(256 + 16 * wave + ln15) * DM_ + ks * 32 + q * 8);
    for (int nt = 4; nt < 10; ++nt) {
        const int c0 = nt * 64;
        f32x4 acc[5];
#pragma unroll
        for (int mt = 0; mt < 5; ++mt) acc[mt] = (f32x4){0.f, 0.f, 0.f, 0.f};
#pragma unroll
        for (int ks = 0; ks < 4; ++ks)
#pragma unroll
            for (int mt = 0; mt < 5; ++mt) {
                short8 afr = *(const short8*)&xs[16 * mt + ln15][ks * 32 + q * 8];
                acc[mt] = __builtin_amdgcn_mfma_f32_16x16x32_bf16(afr, bcur[ks], acc[mt], 0, 0, 0);
            }
        short8 bnxt[4];
        if (nt < 9) {
#pragma unroll
            for (int ks = 0; ks < 4; ++ks)
                bnxt[ks] = *(const short8*)(Wi + (size_t)(c0 + 64 + 16 * wave + ln15) * DM_ + ks * 32 + q * 8);
        }
        const int ch0 = c0 - 256 + c4;
        float cwr[4][4], cbr[4];
#pragma unroll
        for (int j = 0; j < 4; ++j) {
            cbr[j] = cb[ch0 + j];
#pragma unroll
            for (int k = 0; k < 4; ++k) cwr[j][k] = cw[(ch0 + j) * 4 + k];
        }
        __syncthreads();   // prior epilogue's raws reads done
#pragma unroll
        for (int mt = 0; mt < 5; ++mt)
#pragma unroll
            for (int rg = 0; rg < 4; ++rg)
                raws[16 * mt + 4 * q + rg][16 * wave + ln15] = f2bs(acc[mt][rg]);
        __syncthreads();   // raws ready

#pragma unroll
        for (int it = 0; it < 4; ++it) {
            int row = (tid >> 4) + 16 * it;
            float s0[4];
#pragma unroll
            for (int j = 0; j < 4; ++j) s0[j] = cbr[j];
#pragma unroll
            for (int k = 0; k < 4; ++k) {
                S4 rv = *(const S4*)&raws[13 + row + k][c4];
                short rr[4] = { rv.a, rv.b, rv.c, rv.d };
#pragma unroll
                for (int j = 0; j < 4; ++j) s0[j] += bs2f(rr[j]) * cwr[j][k];
            }
            short o[4];
#pragma unroll
            for (int j = 0; j < 4; ++j) { float s = s0[j]; s = s * sigmoidf_(s); o[j] = f2bs(s); }
            S4 s4 = { o[0], o[1], o[2], o[3] };
            *(S4*)(XBC + (rowbase + row) * DXBC_ + ch0) = s4;
        }
#pragma unroll
        for (int ks = 0; ks < 4; ++ks) bcur[ks] = bnxt[ks];
    }

    // ---- dt columns: wave 0 only ----
    if (wave == 0) {
        short8 bfr[4];
#pragma unroll
        for (int ks = 0; ks < 4; ++ks) {
            short8 v = {0, 0, 0, 0, 0, 0, 0, 0};
            if (ln15 < 4) v = *(const short8*)(Wi + (size_t)(640 + ln15) * DM_ + ks * 32 + q * 8);
            bfr[ks] = v;
        }
        const float* dtb = dir ? dtbB : dtbF;
#pragma unroll
        for (int s = 0; s < 4; ++s) {
            f32x4 acc = (f32x4){0.f, 0.f, 0.f, 0.f};
#pragma unroll
            for (int ks = 0; ks < 4; ++ks) {
                short8 afr = *(const short8*)&xs[16 + 16 * s + ln15][ks * 32 + q * 8];
                acc = __builtin_amdgcn_mfma_f32_16x16x32_bf16(afr, bfr[ks], acc, 0, 0, 0);
            }
            if (ln15 < 4) {
                float bias = dtb[ln15];
#pragma unroll
                for (int rg = 0; rg < 4; ++rg)
                    DTV[(rowbase + 16 * s + 4 * q + rg) * NH_ + ln15] = softplusf_(acc[rg] + bias);
            }
        }
    }
}

// ---------------------------------------------------------------------------
// K2 (MFMA, head-merged): per (chunk, b, dir) block handles all 4 heads.
// G = C B^T computed ONCE (head-independent); per h: mask+decay -> M,
// Yd = M Xdt + D*x, st = Xdt (B*dec)^T. grid (32, 16, 2), block 256.
// ---------------------------------------------------------------------------
__global__ __launch_bounds__(256) void k_chunkdiag_mfma(
    const bf16* __restrict__ XBC, const float* __restrict__ DTV,
    const float* __restrict__ AlF, const float* __restrict__ AlB,
    const float* __restrict__ DpF, const float* __restrict__ DpB,
    bf16* __restrict__ Y, bf16* __restrict__ ST, float* __restrict__ CDb)
{
    const int tid = threadIdx.x;
    const int wave = tid >> 6, lane = tid & 63;
    const int ln15 = lane & 15, q = lane >> 4;
    const int c = blockIdx.x, b = blockIdx.y, dir = blockIdx.z;
    const float* Al = dir ? AlB : AlF;
    const float* Dp = dir ? DpB : DpF;
    const int t0 = b * L_ + c * 64;
    const size_t rowbase = (size_t)dir * T_ + t0;

    __shared__ __align__(16) short Bs[64][72];
    __shared__ __align__(16) short Cs[64][72];
    __shared__ __align__(16) short Ms[64][72];
    __shared__ __align__(16) short Bt[64][72];   // raw B transpose [n][l]
    __shared__ __align__(16) short Xt[64][72];   // per-h: Xdt transposed [p][l]
    __shared__ float dtsS[NH_][64], AcsS[NH_][64], decS[NH_][64], rdtS[NH_][64];

    // wave w scans head w
    {
        float Ah = -__expf(Al[wave]);
        float dt = DTV[(rowbase + lane) * NH_ + wave];
        dtsS[wave][lane] = dt;
        rdtS[wave][lane] = frcp_(dt);
        float s = dt * Ah;
#pragma unroll
        for (int off = 1; off < 64; off <<= 1) {
            float t2 = __shfl_up(s, off);
            if (lane >= off) s += t2;
        }
        AcsS[wave][lane] = s;
        float alast = __shfl(s, 63);
        decS[wave][lane] = expneg_(alast - s);
        if (lane == 0) CDb[(((size_t)dir * B_ + b) * NH_ + wave) * NC_ + c] = expneg_(alast);
    }
    for (int u = tid; u < 512; u += 256) {
        int r = u >> 3, g = u & 7;
        size_t base = (rowbase + r) * DXBC_;
        *(short8*)&Bs[r][g * 8] = *(const short8*)(XBC + base + 256 + g * 8);
        *(short8*)&Cs[r][g * 8] = *(const short8*)(XBC + base + 320 + g * 8);
    }
    for (int u = tid; u < 4096; u += 256) {
        int l = u >> 6, n = u & 63;
        Bt[n][l] = bbits(XBC[(rowbase + l) * DXBC_ + 256 + n]);
    }
    __syncthreads();   // B1: everything staged

    // ---- G = C B^T, once, kept in registers ----
    f32x4 g4[4];
#pragma unroll
    for (int ct = 0; ct < 4; ++ct) g4[ct] = (f32x4){0.f, 0.f, 0.f, 0.f};
#pragma unroll
    for (int ks = 0; ks < 2; ++ks) {
        short8 afr = *(const short8*)&Cs[16 * wave + ln15][ks * 32 + q * 8];
#pragma unroll
        for (int ct = 0; ct < 4; ++ct) {
            short8 bfr = *(const short8*)&Bs[16 * ct + ln15][ks * 32 + q * 8];
            g4[ct] = __builtin_amdgcn_mfma_f32_16x16x32_bf16(afr, bfr, g4[ct], 0, 0, 0);
        }
    }

    for (int h = 0; h < NH_; ++h) {
        if (h > 0) __syncthreads();   // prior Xt reads done
        for (int u = tid; u < 4096; u += 256) {
            int l = u >> 6, p = u & 63;
            Xt[p][l] = f2bs(b2f(XBC[(rowbase + l) * DXBC_ + h * HD_ + p]) * dtsS[h][l]);
        }
        __syncthreads();   // Xt ready

        // M = mask+decay of G (own wave strip; no barrier needed)
#pragma unroll
        for (int ct = 0; ct < 4; ++ct)
#pragma unroll
            for (int rg = 0; rg < 4; ++rg) {
                int l = 16 * wave + 4 * q + rg, s = 16 * ct + ln15;
                float m = (s <= l) ? g4[ct][rg] * expneg_(AcsS[h][l] - AcsS[h][s]) : 0.f;
                Ms[l][s] = f2bs(m);
            }
        // Yd = M @ Xdt
        f32x4 a2[4];
#pragma unroll
        for (int ct = 0; ct < 4; ++ct) a2[ct] = (f32x4){0.f, 0.f, 0.f, 0.f};
#pragma unroll
        for (int ks = 0; ks < 2; ++ks) {
            short8 afr = *(const short8*)&Ms[16 * wave + ln15][ks * 32 + q * 8];
#pragma unroll
            for (int ct = 0; ct < 4; ++ct) {
                short8 bfr = *(const short8*)&Xt[16 * ct + ln15][ks * 32 + q * 8];
                a2[ct] = __builtin_amdgcn_mfma_f32_16x16x32_bf16(afr, bfr, a2[ct], 0, 0, 0);
            }
        }
        const float Dh = Dp[h];
#pragma unroll
        for (int ct = 0; ct < 4; ++ct)
#pragma unroll
            for (int rg = 0; rg < 4; ++rg) {
                int l = 16 * wave + 4 * q + rg, p = 16 * ct + ln15;
                float xraw = bs2f(Xt[p][l]) * rdtS[h][l];
                Y[(rowbase + l) * DI_ + h * HD_ + p] = f2b(a2[ct][rg] + Dh * xraw);
            }
        // st: afr = Xt own strip, bfr = Bt scaled by dec[k] in regs
        f32x4 a3[4];
#pragma unroll
        for (int ct = 0; ct < 4; ++ct) a3[ct] = (f32x4){0.f, 0.f, 0.f, 0.f};
#pragma unroll
        for (int ks = 0; ks < 2; ++ks) {
            short8 afr = *(const short8*)&Xt[16 * wave + ln15][ks * 32 + q * 8];
            float dk[8];
#pragma unroll
            for (int j = 0; j < 8; ++j) dk[j] = decS[h][ks * 32 + q * 8 + j];
#pragma unroll
            for (int ct = 0; ct < 4; ++ct) {
                short8 raw = *(const short8*)&Bt[16 * ct + ln15][ks * 32 + q * 8];
                short8 bfr;
#pragma unroll
                for (int j = 0; j < 8; ++j) bfr[j] = f2bs(bs2f(raw[j]) * dk[j]);
                a3[ct] = __builtin_amdgcn_mfma_f32_16x16x32_bf16(afr, bfr, a3[ct], 0, 0, 0);
            }
        }
        size_t sb = ((((size_t)dir * B_ + b) * NC_ + c) * NH_ + h) * 4096;
#pragma unroll
        for (int ct = 0; ct < 4; ++ct)
#pragma unroll
            for (int rg = 0; rg < 4; ++rg) {
                int p = 16 * wave + 4 * q + rg, n = 16 * ct + ln15;
                ST[sb + p * 64 + n] = f2b(a3[ct][rg]);
            }
    }
}

// ---------------------------------------------------------------------------
// K3: inter-chunk scan, in place. grid (256, 2), block 256, 4 els/thread.
// ---------------------------------------------------------------------------
__global__ __launch_bounds__(256) void k_scan(bf16* __restrict__ ST, const float* __restrict__ CDb)
{
    const int tid = threadIdx.x;
    const int dir = blockIdx.y;
    const int bx = blockIdx.x;
    const int b = bx >> 4, h = (bx >> 2) & 3, qt = bx & 3;
    const size_t cdbase = (((size_t)dir * B_ + b) * NH_ + h) * NC_;
    float carry[4] = {0.f, 0.f, 0.f, 0.f};
    for (int c = 0; c < NC_; ++c) {
        const float cd = CDb[cdbase + c];
        size_t base = ((((size_t)dir * B_ + b) * NC_ + c) * NH_ + h) * 4096 + qt * 1024 + tid;
#pragma unroll
        for (int q = 0; q < 4; ++q) {
            float v = b2f(ST[base + q * 256]);
            ST[base + q * 256] = f2b(carry[q]);
            carry[q] = carry[q] * cd + v;
        }
    }
}

// ---------------------------------------------------------------------------
// K4 (MFMA, fused gate+RMSNorm): Yfinal = rmsnorm((Yd + offdiag)*silu(z))*nw.
// Prev-state B-fragments register-prefetched directly from L2 (no Ps LDS,
// 1 barrier total). grid (32, 16, 2), block 256.
// ---------------------------------------------------------------------------
__global__ __launch_bounds__(256) void k_offdiag_fused(
    const bf16* __restrict__ XBC, const float* __restrict__ DTV,
    const float* __restrict__ AlF, const float* __restrict__ AlB,
    const bf16* __restrict__ ST, const bf16* __restrict__ Z,
    const float* __restrict__ nwF, const float* __restrict__ nwB,
    bf16* __restrict__ Y)
{
    const int tid = threadIdx.x;
    const int wave = tid >> 6, lane = tid & 63;
    const int ln15 = lane & 15, q = lane >> 4;
    const int c = blockIdx.x, b = blockIdx.y, dir = blockIdx.z;
    const float* Al = dir ? AlB : AlF;
    const int t0 = b * L_ + c * 64;
    const size_t rowbase = (size_t)dir * T_ + t0;
    const size_t sbase = ((((size_t)dir * B_ + b) * NC_ + c) * NH_) * 4096;

    __shared__ __align__(16) short Cs[64][72];
    __shared__ __align__(16) short Yz[64][264];
    __shared__ float eA[NH_][64];

    // prefetch h=0 prev-state fragments (B-operand layout: ST[p][n])
    short8 pcur[4][2], pnxt[4][2];
#pragma unroll
    for (int ct = 0; ct < 4; ++ct)
#pragma unroll
        for (int ks = 0; ks < 2; ++ks)
            pcur[ct][ks] = *(const short8*)(ST + sbase + (16 * ct + ln15) * 64 + ks * 32 + q * 8);

    {
        float A = -__expf(Al[wave]);
        float s = DTV[(rowbase + lane) * NH_ + wave] * A;
#pragma unroll
        for (int off = 1; off < 64; off <<= 1) {
            float t2 = __shfl_up(s, off);
            if (lane >= off) s += t2;
        }
        eA[wave][lane] = expneg_(s);
    }
    for (int u = tid; u < 512; u += 256) {
        int r = u >> 3, g = u & 7;
        *(short8*)&Cs[r][g * 8] = *(const short8*)(XBC + (rowbase + r) * DXBC_ + 320 + g * 8);
    }
    for (int u = lane; u < 512; u += 64) {
        int r = 16 * wave + (u >> 5), g = u & 31;
        *(short8*)&Yz[r][g * 8] = *(const short8*)(Y + (rowbase + r) * DI_ + g * 8);
    }
    __syncthreads();   // the only barrier

    short8 cfr[2];
#pragma unroll
    for (int ks = 0; ks < 2; ++ks)
        cfr[ks] = *(const short8*)&Cs[16 * wave + ln15][ks * 32 + q * 8];

#pragma unroll
    for (int h = 0; h < NH_; ++h) {
        if (h < 3) {
#pragma unroll
            for (int ct = 0; ct < 4; ++ct)
#pragma unroll
                for (int ks = 0; ks < 2; ++ks)
                    pnxt[ct][ks] = *(const short8*)(ST + sbase + (size_t)(h + 1) * 4096
                                                    + (16 * ct + ln15) * 64 + ks * 32 + q * 8);
        }
        f32x4 acc[4];
#pragma unroll
        for (int ct = 0; ct < 4; ++ct) acc[ct] = (f32x4){0.f, 0.f, 0.f, 0.f};
#pragma unroll
        for (int ks = 0; ks < 2; ++ks)
#pragma unroll
            for (int ct = 0; ct < 4; ++ct)
                acc[ct] = __builtin_amdgcn_mfma_f32_16x16x32_bf16(cfr[ks], pcur[ct][ks], acc[ct], 0, 0, 0);
#pragma unroll
        for (int ct = 0; ct < 4; ++ct)
#pragma unroll
            for (int rg = 0; rg < 4; ++rg) {
                int l = 16 * wave + 4 * q + rg, p = 16 * ct + ln15;
                float yv = bs2f(Yz[l][h * 64 + p]) + acc[ct][rg] * eA[h][l];
                Yz[l][h * 64 + p] = f2bs(yv);   // own wave rows only
            }
#pragma unroll
        for (int ct = 0; ct < 4; ++ct)
#pragma unroll
            for (int ks = 0; ks < 2; ++ks)
                pcur[ct][ks] = pnxt[ct][ks];
    }

    // gate + RMSNorm epilogue (Yz wave-private: no barrier needed)
    const float* nw = dir ? nwB : nwF;
    float nwv[4];
#pragma unroll
    for (int j = 0; j < 4; ++j) nwv[j] = nw[lane * 4 + j];
    for (int rr = 0; rr < 16; ++rr) {
        int row = 16 * wave + rr;
        S4 zv4 = *(const S4*)(Z + (rowbase + row) * DI_ + lane * 4);
        short zr[4] = { zv4.a, zv4.b, zv4.c, zv4.d };
        float v[4]; float ss = 0.f;
#pragma unroll
        for (int j = 0; j < 4; ++j) {
            float yv = bs2f(Yz[row][lane * 4 + j]);
            float zf = bs2f(zr[j]);
            v[j] = yv * zf * sigmoidf_(zf);
            ss += v[j] * v[j];
        }
#pragma unroll
        for (int off = 1; off < 64; off <<= 1) ss += __shfl_xor(ss, off);
        float rn = rsqrtf(ss * (1.f / 256.f) + 1e-5f);
        S4 o = { f2bs(v[0] * rn * nwv[0]), f2bs(v[1] * rn * nwv[1]),
                 f2bs(v[2] * rn * nwv[2]), f2bs(v[3] * rn * nwv[3]) };
        *(S4*)(Y + (rowbase + row) * DI_ + lane * 4) = o;
    }
}

// ---------------------------------------------------------------------------
// K6 (MFMA): out[t] = y_f[t] @ Wo_f^T + y_b[flip(t)] @ Wo_b^T.
// grid 512, block 512 (8 waves: 4 M-strips x 2 N-halves), LDS-staged Wo.
// ---------------------------------------------------------------------------
__global__ __launch_bounds__(512) void k_outproj_mfma(
    const bf16* __restrict__ Y, const bf16* __restrict__ WoFb, const bf16* __restrict__ WoBb,
    float* __restrict__ out)
{
    const int tid = threadIdx.x;
    const int wave = tid >> 6, lane = tid & 63;
    const int ln15 = lane & 15, q = lane >> 4;
    const int mt = wave & 3, nh = wave >> 2;
    const int t0 = blockIdx.x * 64;
    const int batch = t0 >> 11;
    const int l0 = t0 & (L_ - 1);

    __shared__ __align__(16) short ys[64][72];
    __shared__ __align__(16) short wsm[128][72];

    f32x4 acc[4];
#pragma unroll
    for (int ct = 0; ct < 4; ++ct) acc[ct] = (f32x4){0.f, 0.f, 0.f, 0.f};

    for (int dir = 0; dir < 2; ++dir) {
        const bf16* Wo = dir ? WoBb : WoFb;
        for (int kt = 0; kt < 4; ++kt) {
            const int k0 = kt * 64;
            __syncthreads();
            {
                int u = tid;
                int r = u >> 3, g = u & 7;
                int tsrc = dir ? (batch * L_ + (L_ - 1 - (l0 + r))) : (t0 + r);
                *(short8*)&ys[r][g * 8] =
                    *(const short8*)(Y + ((size_t)dir * T_ + tsrc) * DI_ + k0 + g * 8);
            }
            for (int u = tid; u < 1024; u += 512) {
                int m = u >> 3, g = u & 7;
                *(short8*)&wsm[m][g * 8] = *(const short8*)(Wo + (size_t)m * DI_ + k0 + g * 8);
            }
            __syncthreads();
#pragma unroll
            for (int ks = 0; ks < 2; ++ks) {
                short8 afr = *(const short8*)&ys[16 * mt + ln15][ks * 32 + q * 8];
#pragma unroll
                for (int ct = 0; ct < 4; ++ct) {
                    short8 bfr = *(const short8*)&wsm[16 * (4 * nh + ct) + ln15][ks * 32 + q * 8];
                    acc[ct] = __builtin_amdgcn_mfma_f32_16x16x32_bf16(afr, bfr, acc[ct], 0, 0, 0);
                }
            }
        }
    }
#pragma unroll
    for (int ct = 0; ct < 4; ++ct)
#pragma unroll
        for (int rg = 0; rg < 4; ++rg) {
            int row = 16 * mt + 4 * q + rg, col = 16 * (4 * nh + ct) + ln15;
            out[((size_t)(t0 + row)) * DM_ + col] = acc[ct][rg];
        }
}

// ---------------------------------------------------------------------------
extern "C" void kernel_launch(void* const* d_in, const int* in_sizes, int n_in,
                              void* d_out, int out_size, void* d_ws, size_t ws_size,
                              hipStream_t stream)
{
    const float* x    = (const float*)d_in[0];
    const float* WiF  = (const float*)d_in[1];
    const float* cwF  = (const float*)d_in[2];
    const float* cbF  = (const float*)d_in[3];
    const float* dtbF = (const float*)d_in[4];
    const float* AlF  = (const float*)d_in[5];
    const float* DpF  = (const float*)d_in[6];
    const float* nwF  = (const float*)d_in[7];
    const float* WoF  = (const float*)d_in[8];
    const float* WiB  = (const float*)d_in[9];
    const float* cwB  = (const float*)d_in[10];
    const float* cbB  = (const float*)d_in[11];
    const float* dtbB = (const float*)d_in[12];
    const float* AlB  = (const float*)d_in[13];
    const float* DpB  = (const float*)d_in[14];
    const float* nwB  = (const float*)d_in[15];
    const float* WoB  = (const float*)d_in[16];

    const size_t nZ   = (size_t)2 * T_ * DI_;       // bf16
    const size_t nXBC = (size_t)2 * T_ * DXBC_;     // bf16
    const size_t nY   = (size_t)2 * T_ * DI_;       // bf16
    const size_t nST  = (size_t)2 * B_ * NC_ * NH_ * HD_ * DS_;  // bf16
    const size_t nWb  = (size_t)2 * NWI + 2 * NWO;  // bf16 weight copies
    const size_t nDTV = (size_t)2 * T_ * NH_;       // f32
    const size_t nCD  = (size_t)2 * B_ * NH_ * NC_; // f32
    const size_t need = (nZ + nXBC + nY + nST + nWb) * sizeof(bf16)
                      + (nDTV + nCD) * sizeof(float);
    if (ws_size < need) return;

    char* p = (char*)d_ws;
    bf16* Z    = (bf16*)p;            p += nZ * sizeof(bf16);
    bf16* XBC  = (bf16*)p;            p += nXBC * sizeof(bf16);
    bf16* Yb   = (bf16*)p;            p += nY * sizeof(bf16);
    bf16* ST   = (bf16*)p;            p += nST * sizeof(bf16);
    bf16* WiFb = (bf16*)p;            p += (size_t)NWI * sizeof(bf16);
    bf16* WiBb = (bf16*)p;            p += (size_t)NWI * sizeof(bf16);
    bf16* WoFb = (bf16*)p;            p += (size_t)NWO * sizeof(bf16);
    bf16* WoBb = (bf16*)p;            p += (size_t)NWO * sizeof(bf16);
    float* DTV = (float*)p;           p += nDTV * sizeof(float);
    float* CDb = (float*)p;

    k_prep<<<128, 256, 0, stream>>>(WiF, WiB, WoF, WoB, WiFb, WiBb, WoFb, WoBb);
    k_inproj_mfma<<<dim3(512, 2), 256, 0, stream>>>(x, WiFb, WiBb, cwF, cbF, cwB, cbB,
                                                    dtbF, dtbB, Z, XBC, DTV);
    k_chunkdiag_mfma<<<dim3(NC_, B_, 2), 256, 0, stream>>>(XBC, DTV, AlF, AlB, DpF, DpB,
                                                           Yb, ST, CDb);
    k_scan<<<dim3(256, 2), 256, 0, stream>>>(ST, CDb);
    k_offdiag_fused<<<dim3(NC_, B_, 2), 256, 0, stream>>>(XBC, DTV, AlF, AlB, ST, Z,
                                                          nwF, nwB, Yb);
    k_outproj_mfma<<<dim3(512), 512, 0, stream>>>(Yb, WoFb, WoBb, (float*)d_out);
}

// Round 12
// 242.573 us; speedup vs baseline: 1.0386x; 1.0386x over previous
//
#include <hip/hip_runtime.h>
#include <hip/hip_bf16.h>
#include <cmath>

#define B_    16
#define L_    2048
#define T_    32768   // B_*L_
#define DM_   128
#define DI_   256
#define DXBC_ 384
#define DS_   64
#define HD_   64
#define NH_   4
#define NC_   32      // chunks per sequence (L_/64)

typedef __hip_bfloat16 bf16;
typedef __attribute__((ext_vector_type(8))) short short8;
typedef __attribute__((ext_vector_type(4))) float f32x4;

__device__ __forceinline__ float b2f(bf16 v) { return __bfloat162float(v); }
__device__ __forceinline__ bf16  f2b(float f) { return __float2bfloat16(f); }
__device__ __forceinline__ short f2bs(float f) { bf16 h = __float2bfloat16(f); return *reinterpret_cast<short*>(&h); }
__device__ __forceinline__ float bs2f(short s) { bf16 h = *reinterpret_cast<bf16*>(&s); return __bfloat162float(h); }
// fast transcendentals: v_exp_f32 / v_log_f32 / v_rcp_f32 (1-2 ulp, fine for bf16)
__device__ __forceinline__ float frcp_(float x) { return __builtin_amdgcn_rcpf(x); }
__device__ __forceinline__ float sigmoidf_(float x) { return frcp_(1.f + __expf(-x)); }
__device__ __forceinline__ float softplusf_(float x) { return (x > 20.f) ? x : __logf(1.f + __expf(x)); }
__device__ __forceinline__ float expneg_(float x) { return __expf(fminf(x, 0.f)); }

struct __align__(8) S4 { short a, b, c, d; };

#define NWI 82432   // 644*128
#define NWO 32768   // 128*256

// ---------------------------------------------------------------------------
// K0: one-time f32 -> bf16 conversion of x, Wi_f/b, Wo_f/b.
// ---------------------------------------------------------------------------
__global__ __launch_bounds__(256) void k_prep(
    const float* __restrict__ x,
    const float* __restrict__ WiF, const float* __restrict__ WiB,
    const float* __restrict__ WoF, const float* __restrict__ WoB,
    bf16* __restrict__ Xb, bf16* __restrict__ WiFb, bf16* __restrict__ WiBb,
    bf16* __restrict__ WoFb, bf16* __restrict__ WoBb)
{
    const int gid = blockIdx.x * 256 + threadIdx.x;
    const int stride = gridDim.x * 256;
    for (int i = gid; i < 1048576; i += stride) {   // T_*DM_/4
        float4 v = ((const float4*)x)[i];
        S4 s = { f2bs(v.x), f2bs(v.y), f2bs(v.z), f2bs(v.w) };
        ((S4*)Xb)[i] = s;
    }
    for (int i = gid; i < NWI / 4; i += stride) {
        float4 v = ((const float4*)WiF)[i];
        S4 s = { f2bs(v.x), f2bs(v.y), f2bs(v.z), f2bs(v.w) };
        ((S4*)WiFb)[i] = s;
        v = ((const float4*)WiB)[i];
        S4 t = { f2bs(v.x), f2bs(v.y), f2bs(v.z), f2bs(v.w) };
        ((S4*)WiBb)[i] = t;
    }
    for (int i = gid; i < NWO / 4; i += stride) {
        float4 v = ((const float4*)WoF)[i];
        S4 s = { f2bs(v.x), f2bs(v.y), f2bs(v.z), f2bs(v.w) };
        ((S4*)WoFb)[i] = s;
        v = ((const float4*)WoB)[i];
        S4 t = { f2bs(v.x), f2bs(v.y), f2bs(v.z), f2bs(v.w) };
        ((S4*)WoBb)[i] = t;
    }
}

// ---------------------------------------------------------------------------
// K1 (MFMA): in_proj GEMM; weights direct from global (L2-resident).
// Z tiles: swapped orientation (A=W, B=x) -> S4 store straight from acc.
// Conv tiles: A=x orientation + raws round-trip; conv weights hoisted.
// dt: wave-0 MFMA. grid (512, 2), block 256. 13 barriers total.
// ---------------------------------------------------------------------------
__global__ __launch_bounds__(256) void k_inproj_mfma(
    const bf16* __restrict__ Xb, const bf16* __restrict__ WiFb, const bf16* __restrict__ WiBb,
    const float* __restrict__ cwF, const float* __restrict__ cbF,
    const float* __restrict__ cwB, const float* __restrict__ cbB,
    const float* __restrict__ dtbF, const float* __restrict__ dtbB,
    bf16* __restrict__ Z, bf16* __restrict__ XBC, float* __restrict__ DTV)
{
    const int tid  = threadIdx.x;
    const int wave = tid >> 6, lane = tid & 63;
    const int ln15 = lane & 15, q = lane >> 4;
    const int dir  = blockIdx.y;
    const bf16* Wi = dir ? WiBb : WiFb;
    const int t0 = blockIdx.x * 64;
    const int batch = t0 >> 11, l0 = t0 & (L_ - 1);
    const size_t rowbase = (size_t)dir * T_ + t0;

    __shared__ __align__(16) short xs[80][136];    // tokens l0-16 .. l0+63
    __shared__ __align__(16) short raws[80][80];   // conv scratch

    for (int u = tid; u < 1280; u += 256) {
        int r = u >> 4, g = u & 15;
        int l = l0 - 16 + r;
        short8 v = {0, 0, 0, 0, 0, 0, 0, 0};
        if (l >= 0) {
            int sl = dir ? (L_ - 1 - l) : l;
            v = *(const short8*)(Xb + ((size_t)batch * L_ + sl) * DM_ + g * 8);
        }
        *(short8*)&xs[r][g * 8] = v;
    }
    __syncthreads();

    // ---- Z tiles (4): swapped orientation, zero barriers ----
#pragma unroll
    for (int zt = 0; zt < 4; ++zt) {
        const int c0 = zt * 64;
        short8 wf[4];
#pragma unroll
        for (int ks = 0; ks < 4; ++ks)
            wf[ks] = *(const short8*)(Wi + (size_t)(c0 + 16 * wave + ln15) * DM_ + ks * 32 + q * 8);
#pragma unroll
        for (int ct = 0; ct < 4; ++ct) {
            f32x4 acc = (f32x4){0.f, 0.f, 0.f, 0.f};
#pragma unroll
            for (int ks = 0; ks < 4; ++ks) {
                short8 xf = *(const short8*)&xs[16 + 16 * ct + ln15][ks * 32 + q * 8];
                acc = __builtin_amdgcn_mfma_f32_16x16x32_bf16(wf[ks], xf, acc, 0, 0, 0);
            }
            S4 s = { f2bs(acc[0]), f2bs(acc[1]), f2bs(acc[2]), f2bs(acc[3]) };
            *(S4*)(Z + (rowbase + 16 * ct + ln15) * DI_ + c0 + 16 * wave + 4 * q) = s;
        }
    }

    // ---- conv tiles (6): raws round-trip + next-tile weight prefetch ----
    const float* cw = dir ? cwB : cwF;
    const float* cb = dir ? cbB : cbF;
    const int c4 = (tid & 15) * 4;
    short8 bcur[4];
#pragma unroll
    for (int ks = 0; ks < 4; ++ks)
        bcur[ks] = *(const short8*)(Wi + (size_t)(256 + 16 * wave + ln15) * DM_ + ks * 32 + q * 8);
    for (int nt = 4; nt < 10; ++nt) {
        const int c0 = nt * 64;
        f32x4 acc[5];
#pragma unroll
        for (int mt = 0; mt < 5; ++mt) acc[mt] = (f32x4){0.f, 0.f, 0.f, 0.f};
#pragma unroll
        for (int ks = 0; ks < 4; ++ks)
#pragma unroll
            for (int mt = 0; mt < 5; ++mt) {
                short8 afr = *(const short8*)&xs[16 * mt + ln15][ks * 32 + q * 8];
                acc[mt] = __builtin_amdgcn_mfma_f32_16x16x32_bf16(afr, bcur[ks], acc[mt], 0, 0, 0);
            }
        short8 bnxt[4];
        if (nt < 9) {
#pragma unroll
            for (int ks = 0; ks < 4; ++ks)
                bnxt[ks] = *(const short8*)(Wi + (size_t)(c0 + 64 + 16 * wave + ln15) * DM_ + ks * 32 + q * 8);
        }
        const int ch0 = c0 - 256 + c4;
        float cwr[4][4], cbr[4];
#pragma unroll
        for (int j = 0; j < 4; ++j) {
            cbr[j] = cb[ch0 + j];
#pragma unroll
            for (int k = 0; k < 4; ++k) cwr[j][k] = cw[(ch0 + j) * 4 + k];
        }
        __syncthreads();   // prior epilogue's raws reads done
#pragma unroll
        for (int mt = 0; mt < 5; ++mt)
#pragma unroll
            for (int rg = 0; rg < 4; ++rg)
                raws[16 * mt + 4 * q + rg][16 * wave + ln15] = f2bs(acc[mt][rg]);
        __syncthreads();   // raws ready

#pragma unroll
        for (int it = 0; it < 4; ++it) {
            int row = (tid >> 4) + 16 * it;
            float s0[4];
#pragma unroll
            for (int j = 0; j < 4; ++j) s0[j] = cbr[j];
#pragma unroll
            for (int k = 0; k < 4; ++k) {
                S4 rv = *(const S4*)&raws[13 + row + k][c4];
                short rr[4] = { rv.a, rv.b, rv.c, rv.d };
#pragma unroll
                for (int j = 0; j < 4; ++j) s0[j] += bs2f(rr[j]) * cwr[j][k];
            }
            short o[4];
#pragma unroll
            for (int j = 0; j < 4; ++j) { float s = s0[j]; s = s * sigmoidf_(s); o[j] = f2bs(s); }
            S4 s4 = { o[0], o[1], o[2], o[3] };
            *(S4*)(XBC + (rowbase + row) * DXBC_ + ch0) = s4;
        }
#pragma unroll
        for (int ks = 0; ks < 4; ++ks) bcur[ks] = bnxt[ks];
    }

    // ---- dt columns: wave 0 only ----
    if (wave == 0) {
        short8 bfr[4];
#pragma unroll
        for (int ks = 0; ks < 4; ++ks) {
            short8 v = {0, 0, 0, 0, 0, 0, 0, 0};
            if (ln15 < 4) v = *(const short8*)(Wi + (size_t)(640 + ln15) * DM_ + ks * 32 + q * 8);
            bfr[ks] = v;
        }
        const float* dtb = dir ? dtbB : dtbF;
#pragma unroll
        for (int s = 0; s < 4; ++s) {
            f32x4 acc = (f32x4){0.f, 0.f, 0.f, 0.f};
#pragma unroll
            for (int ks = 0; ks < 4; ++ks) {
                short8 afr = *(const short8*)&xs[16 + 16 * s + ln15][ks * 32 + q * 8];
                acc = __builtin_amdgcn_mfma_f32_16x16x32_bf16(afr, bfr[ks], acc, 0, 0, 0);
            }
            if (ln15 < 4) {
                float bias = dtb[ln15];
#pragma unroll
                for (int rg = 0; rg < 4; ++rg)
                    DTV[(rowbase + 16 * s + 4 * q + rg) * NH_ + ln15] = softplusf_(acc[rg] + bias);
            }
        }
    }
}

// ---------------------------------------------------------------------------
// K2 (MFMA): per (chunk, b, h, dir): G = C B^T, mask+decay, Yd = M Xdt + D*x,
// chunk states st = (Xdt*dec)^T B. grid: (32, 64, 2), block 256, 2 barriers.
// ---------------------------------------------------------------------------
__global__ __launch_bounds__(256) void k_chunkdiag_mfma(
    const bf16* __restrict__ XBC, const float* __restrict__ DTV,
    const float* __restrict__ AlF, const float* __restrict__ AlB,
    const float* __restrict__ DpF, const float* __restrict__ DpB,
    bf16* __restrict__ Y, bf16* __restrict__ ST, float* __restrict__ CDb)
{
    const int tid = threadIdx.x;
    const int wave = tid >> 6, lane = tid & 63;
    const int ln15 = lane & 15, q = lane >> 4;
    const int c = blockIdx.x;
    const int b = blockIdx.y >> 2;
    const int h = blockIdx.y & 3;
    const int dir = blockIdx.z;
    const float Ah = -__expf((dir ? AlB : AlF)[h]);
    const float Dh = (dir ? DpB : DpF)[h];
    const int t0 = b * L_ + c * 64;
    const size_t rowbase = (size_t)dir * T_ + t0;

    __shared__ __align__(16) short Bs[64][72];
    __shared__ __align__(16) short Cs[64][72];   // aliased as M after step 1
    __shared__ __align__(16) short Xt[64][72];   // Xdt transposed: Xt[p][l]
    __shared__ __align__(16) short Bt[64][72];   // Bt[n][l] = dec[l]*B[l][n]
    __shared__ float dts[64];
    __shared__ float rdts[64];
    __shared__ float Acs[64];
    __shared__ float decs[64];

    // wave-0 shuffle scan for Acs/decs
    if (tid < 64) {
        int l = tid;
        float dt = DTV[(rowbase + l) * NH_ + h];
        dts[l] = dt;
        rdts[l] = frcp_(dt);
        float s = dt * Ah;
#pragma unroll
        for (int off = 1; off < 64; off <<= 1) {
            float t2 = __shfl_up(s, off);
            if (l >= off) s += t2;
        }
        Acs[l] = s;
        float alast = __shfl(s, 63);
        decs[l] = expneg_(alast - s);
        if (l == 0) CDb[(((size_t)dir * B_ + b) * NH_ + h) * NC_ + c] = expneg_(alast);
    }
    __syncthreads();   // B1

    for (int u = tid; u < 512; u += 256) {
        int r = u >> 3, g = u & 7;
        size_t base = (rowbase + r) * DXBC_;
        *(short8*)&Bs[r][g * 8] = *(const short8*)(XBC + base + 256 + g * 8);
        *(short8*)&Cs[r][g * 8] = *(const short8*)(XBC + base + 320 + g * 8);
    }
    for (int u = tid; u < 4096; u += 256) {
        int l = u >> 6, p = u & 63;
        Xt[p][l] = f2bs(b2f(XBC[(rowbase + l) * DXBC_ + h * HD_ + p]) * dts[l]);
    }
    for (int u = tid; u < 4096; u += 256) {
        int l = u >> 6, n = u & 63;
        Bt[n][l] = f2bs(b2f(XBC[(rowbase + l) * DXBC_ + 256 + n]) * decs[l]);
    }
    __syncthreads();   // B2 — last barrier

    // step 1: G = C B^T
    f32x4 a1[4];
#pragma unroll
    for (int ct = 0; ct < 4; ++ct) a1[ct] = (f32x4){0.f, 0.f, 0.f, 0.f};
#pragma unroll
    for (int ks = 0; ks < 2; ++ks) {
        short8 afr = *(const short8*)&Cs[16 * wave + ln15][ks * 32 + q * 8];
#pragma unroll
        for (int ct = 0; ct < 4; ++ct) {
            short8 bfr = *(const short8*)&Bs[16 * ct + ln15][ks * 32 + q * 8];
            a1[ct] = __builtin_amdgcn_mfma_f32_16x16x32_bf16(afr, bfr, a1[ct], 0, 0, 0);
        }
    }
#pragma unroll
    for (int ct = 0; ct < 4; ++ct)
#pragma unroll
        for (int rg = 0; rg < 4; ++rg) {
            int l = 16 * wave + 4 * q + rg, s = 16 * ct + ln15;
            float m = (s <= l) ? a1[ct][rg] * expneg_(Acs[l] - Acs[s]) : 0.f;
            Cs[l][s] = f2bs(m);   // own wave strip only
        }
    // step 2: Yd = M @ Xdt
    f32x4 a2[4];
#pragma unroll
    for (int ct = 0; ct < 4; ++ct) a2[ct] = (f32x4){0.f, 0.f, 0.f, 0.f};
#pragma unroll
    for (int ks = 0; ks < 2; ++ks) {
        short8 afr = *(const short8*)&Cs[16 * wave + ln15][ks * 32 + q * 8];
#pragma unroll
        for (int ct = 0; ct < 4; ++ct) {
            short8 bfr = *(const short8*)&Xt[16 * ct + ln15][ks * 32 + q * 8];
            a2[ct] = __builtin_amdgcn_mfma_f32_16x16x32_bf16(afr, bfr, a2[ct], 0, 0, 0);
        }
    }
#pragma unroll
    for (int ct = 0; ct < 4; ++ct)
#pragma unroll
        for (int rg = 0; rg < 4; ++rg) {
            int l = 16 * wave + 4 * q + rg, p = 16 * ct + ln15;
            // xraw = Xt/dt (bf16-rounded product / f32 dt; softplus>0 so safe)
            float xraw = bs2f(Xt[p][l]) * rdts[l];
            Y[(rowbase + l) * DI_ + h * HD_ + p] = f2b(a2[ct][rg] + Dh * xraw);
        }
    // step 3: st[p][n]
    f32x4 a3[4];
#pragma unroll
    for (int ct = 0; ct < 4; ++ct) a3[ct] = (f32x4){0.f, 0.f, 0.f, 0.f};
#pragma unroll
    for (int ks = 0; ks < 2; ++ks) {
        short8 afr = *(const short8*)&Xt[16 * wave + ln15][ks * 32 + q * 8];
#pragma unroll
        for (int ct = 0; ct < 4; ++ct) {
            short8 bfr = *(const short8*)&Bt[16 * ct + ln15][ks * 32 + q * 8];
            a3[ct] = __builtin_amdgcn_mfma_f32_16x16x32_bf16(afr, bfr, a3[ct], 0, 0, 0);
        }
    }
    size_t sb = ((((size_t)dir * B_ + b) * NC_ + c) * NH_ + h) * 4096;
#pragma unroll
    for (int ct = 0; ct < 4; ++ct)
#pragma unroll
        for (int rg = 0; rg < 4; ++rg) {
            int p = 16 * wave + 4 * q + rg, n = 16 * ct + ln15;
            ST[sb + p * 64 + n] = f2b(a3[ct][rg]);
        }
}

// ---------------------------------------------------------------------------
// K3: inter-chunk scan, in place. grid (1024, 2), block 256, 1 el/thread,
// next-chunk load prefetched past the current store (latency overlap).
// ---------------------------------------------------------------------------
__global__ __launch_bounds__(256) void k_scan(bf16* __restrict__ ST, const float* __restrict__ CDb)
{
    const int tid = threadIdx.x;
    const int dir = blockIdx.y;
    const int bx = blockIdx.x;                 // 16 b x 4 h x 16 seg
    const int b = bx >> 6, h = (bx >> 4) & 3, seg = bx & 15;
    const size_t cdbase = (((size_t)dir * B_ + b) * NH_ + h) * NC_;
    const size_t base0 = (((size_t)dir * B_ + b) * NC_ * NH_ + h) * 4096 + seg * 256 + tid;
    const size_t cstride = (size_t)NH_ * 4096;   // chunk stride in elements

    float carry = 0.f;
    float v = b2f(ST[base0]);
    for (int c = 0; c < NC_; ++c) {
        float vn = 0.f;
        if (c < NC_ - 1) vn = b2f(ST[base0 + (size_t)(c + 1) * cstride]);
        ST[base0 + (size_t)c * cstride] = f2b(carry);
        carry = carry * CDb[cdbase + c] + v;
        v = vn;
    }
}

// ---------------------------------------------------------------------------
// K4 (MFMA, fused gate+RMSNorm): Yfinal = rmsnorm((Yd + offdiag)*silu(z))*nw.
// grid: (32, 16, 2), block 256. Yz strictly wave-private; Acs via wave scans.
// ---------------------------------------------------------------------------
__global__ __launch_bounds__(256) void k_offdiag_fused(
    const bf16* __restrict__ XBC, const float* __restrict__ DTV,
    const float* __restrict__ AlF, const float* __restrict__ AlB,
    const bf16* __restrict__ ST, const bf16* __restrict__ Z,
    const float* __restrict__ nwF, const float* __restrict__ nwB,
    bf16* __restrict__ Y)
{
    const int tid = threadIdx.x;
    const int wave = tid >> 6, lane = tid & 63;
    const int ln15 = lane & 15, q = lane >> 4;
    const int c = blockIdx.x, b = blockIdx.y, dir = blockIdx.z;
    const float* Al = dir ? AlB : AlF;
    const int t0 = b * L_ + c * 64;
    const size_t rowbase = (size_t)dir * T_ + t0;

    __shared__ __align__(16) short Cs[64][72];
    __shared__ __align__(16) short Ps[64][72];
    __shared__ __align__(16) short Yz[64][264];
    __shared__ float eA[NH_][64];

    {
        float A = -__expf(Al[wave]);
        float s = DTV[(rowbase + lane) * NH_ + wave] * A;
#pragma unroll
        for (int off = 1; off < 64; off <<= 1) {
            float t2 = __shfl_up(s, off);
            if (lane >= off) s += t2;
        }
        eA[wave][lane] = expneg_(s);
    }
    for (int u = tid; u < 512; u += 256) {
        int r = u >> 3, g = u & 7;
        *(short8*)&Cs[r][g * 8] = *(const short8*)(XBC + (rowbase + r) * DXBC_ + 320 + g * 8);
    }
    for (int u = lane; u < 512; u += 64) {
        int r = 16 * wave + (u >> 5), g = u & 31;
        *(short8*)&Yz[r][g * 8] = *(const short8*)(Y + (rowbase + r) * DI_ + g * 8);
    }

    for (int h = 0; h < NH_; ++h) {
        __syncthreads();
        size_t sb = ((((size_t)dir * B_ + b) * NC_ + c) * NH_ + h) * 4096;
        for (int u = tid; u < 512; u += 256) {
            int r = u >> 3, g = u & 7;
            *(short8*)&Ps[r][g * 8] = *(const short8*)(ST + sb + r * 64 + g * 8);
        }
        __syncthreads();

        f32x4 acc[4];
#pragma unroll
        for (int ct = 0; ct < 4; ++ct) acc[ct] = (f32x4){0.f, 0.f, 0.f, 0.f};
#pragma unroll
        for (int ks = 0; ks < 2; ++ks) {
            short8 afr = *(const short8*)&Cs[16 * wave + ln15][ks * 32 + q * 8];
#pragma unroll
            for (int ct = 0; ct < 4; ++ct) {
                short8 bfr = *(const short8*)&Ps[16 * ct + ln15][ks * 32 + q * 8];
                acc[ct] = __builtin_amdgcn_mfma_f32_16x16x32_bf16(afr, bfr, acc[ct], 0, 0, 0);
            }
        }
#pragma unroll
        for (int ct = 0; ct < 4; ++ct)
#pragma unroll
            for (int rg = 0; rg < 4; ++rg) {
                int l = 16 * wave + 4 * q + rg, p = 16 * ct + ln15;
                float yv = bs2f(Yz[l][h * 64 + p]) + acc[ct][rg] * eA[h][l];
                Yz[l][h * 64 + p] = f2bs(yv);   // own wave rows only
            }
    }

    // gate + RMSNorm epilogue (Yz wave-private: no barrier needed)
    const float* nw = dir ? nwB : nwF;
    float nwv[4];
#pragma unroll
    for (int j = 0; j < 4; ++j) nwv[j] = nw[lane * 4 + j];
    for (int rr = 0; rr < 16; ++rr) {
        int row = 16 * wave + rr;
        S4 zv4 = *(const S4*)(Z + (rowbase + row) * DI_ + lane * 4);
        short zr[4] = { zv4.a, zv4.b, zv4.c, zv4.d };
        float v[4]; float ss = 0.f;
#pragma unroll
        for (int j = 0; j < 4; ++j) {
            float yv = bs2f(Yz[row][lane * 4 + j]);
            float zf = bs2f(zr[j]);
            v[j] = yv * zf * sigmoidf_(zf);
            ss += v[j] * v[j];
        }
#pragma unroll
        for (int off = 1; off < 64; off <<= 1) ss += __shfl_xor(ss, off);
        float rn = rsqrtf(ss * (1.f / 256.f) + 1e-5f);
        S4 o = { f2bs(v[0] * rn * nwv[0]), f2bs(v[1] * rn * nwv[1]),
                 f2bs(v[2] * rn * nwv[2]), f2bs(v[3] * rn * nwv[3]) };
        *(S4*)(Y + (rowbase + row) * DI_ + lane * 4) = o;
    }
}

// ---------------------------------------------------------------------------
// K6 (MFMA): out[t] = y_f[t] @ Wo_f^T + y_b[flip(t)] @ Wo_b^T.
// grid 512, block 512 (8 waves: 4 M-strips x 2 N-halves), LDS-staged Wo.
// ---------------------------------------------------------------------------
__global__ __launch_bounds__(512) void k_outproj_mfma(
    const bf16* __restrict__ Y, const bf16* __restrict__ WoFb, const bf16* __restrict__ WoBb,
    float* __restrict__ out)
{
    const int tid = threadIdx.x;
    const int wave = tid >> 6, lane = tid & 63;
    const int ln15 = lane & 15, q = lane >> 4;
    const int mt = wave & 3, nh = wave >> 2;
    const int t0 = blockIdx.x * 64;
    const int batch = t0 >> 11;
    const int l0 = t0 & (L_ - 1);

    __shared__ __align__(16) short ys[64][72];
    __shared__ __align__(16) short wsm[128][72];

    f32x4 acc[4];
#pragma unroll
    for (int ct = 0; ct < 4; ++ct) acc[ct] = (f32x4){0.f, 0.f, 0.f, 0.f};

    for (int dir = 0; dir < 2; ++dir) {
        const bf16* Wo = dir ? WoBb : WoFb;
        for (int kt = 0; kt < 4; ++kt) {
            const int k0 = kt * 64;
            __syncthreads();
            {
                int u = tid;
                int r = u >> 3, g = u & 7;
                int tsrc = dir ? (batch * L_ + (L_ - 1 - (l0 + r))) : (t0 + r);
                *(short8*)&ys[r][g * 8] =
                    *(const short8*)(Y + ((size_t)dir * T_ + tsrc) * DI_ + k0 + g * 8);
            }
            for (int u = tid; u < 1024; u += 512) {
                int m = u >> 3, g = u & 7;
                *(short8*)&wsm[m][g * 8] = *(const short8*)(Wo + (size_t)m * DI_ + k0 + g * 8);
            }
            __syncthreads();
#pragma unroll
            for (int ks = 0; ks < 2; ++ks) {
                short8 afr = *(const short8*)&ys[16 * mt + ln15][ks * 32 + q * 8];
#pragma unroll
                for (int ct = 0; ct < 4; ++ct) {
                    short8 bfr = *(const short8*)&wsm[16 * (4 * nh + ct) + ln15][ks * 32 + q * 8];
                    acc[ct] = __builtin_amdgcn_mfma_f32_16x16x32_bf16(afr, bfr, acc[ct], 0, 0, 0);
                }
            }
        }
    }
#pragma unroll
    for (int ct = 0; ct < 4; ++ct)
#pragma unroll
        for (int rg = 0; rg < 4; ++rg) {
            int row = 16 * mt + 4 * q + rg, col = 16 * (4 * nh + ct) + ln15;
            out[((size_t)(t0 + row)) * DM_ + col] = acc[ct][rg];
        }
}

// ---------------------------------------------------------------------------
extern "C" void kernel_launch(void* const* d_in, const int* in_sizes, int n_in,
                              void* d_out, int out_size, void* d_ws, size_t ws_size,
                              hipStream_t stream)
{
    const float* x    = (const float*)d_in[0];
    const float* WiF  = (const float*)d_in[1];
    const float* cwF  = (const float*)d_in[2];
    const float* cbF  = (const float*)d_in[3];
    const float* dtbF = (const float*)d_in[4];
    const float* AlF  = (const float*)d_in[5];
    const float* DpF  = (const float*)d_in[6];
    const float* nwF  = (const float*)d_in[7];
    const float* WoF  = (const float*)d_in[8];
    const float* WiB  = (const float*)d_in[9];
    const float* cwB  = (const float*)d_in[10];
    const float* cbB  = (const float*)d_in[11];
    const float* dtbB = (const float*)d_in[12];
    const float* AlB  = (const float*)d_in[13];
    const float* DpB  = (const float*)d_in[14];
    const float* nwB  = (const float*)d_in[15];
    const float* WoB  = (const float*)d_in[16];

    const size_t nZ   = (size_t)2 * T_ * DI_;       // bf16
    const size_t nXBC = (size_t)2 * T_ * DXBC_;     // bf16
    const size_t nY   = (size_t)2 * T_ * DI_;       // bf16
    const size_t nST  = (size_t)2 * B_ * NC_ * NH_ * HD_ * DS_;  // bf16
    const size_t nWb  = (size_t)2 * NWI + 2 * NWO;  // bf16 weight copies
    const size_t nDTV = (size_t)2 * T_ * NH_;       // f32
    const size_t nCD  = (size_t)2 * B_ * NH_ * NC_; // f32
    const size_t need = (nZ + nXBC + nY + nST + nWb) * sizeof(bf16)
                      + (nDTV + nCD) * sizeof(float);
    if (ws_size < need) return;

    char* p = (char*)d_ws;
    bf16* Z    = (bf16*)p;            p += nZ * sizeof(bf16);
    bf16* XBC  = (bf16*)p;            p += nXBC * sizeof(bf16);
    bf16* Yb   = (bf16*)p;            p += nY * sizeof(bf16);
    bf16* ST   = (bf16*)p;            p += nST * sizeof(bf16);
    bf16* WiFb = (bf16*)p;            p += (size_t)NWI * sizeof(bf16);
    bf16* WiBb = (bf16*)p;            p += (size_t)NWI * sizeof(bf16);
    bf16* WoFb = (bf16*)p;            p += (size_t)NWO * sizeof(bf16);
    bf16* WoBb = (bf16*)p;            p += (size_t)NWO * sizeof(bf16);
    float* DTV = (float*)p;           p += nDTV * sizeof(float);
    float* CDb = (float*)p;
    bf16* Xb   = ST;   // alias: Xb dead before ST is written (k_chunkdiag)

    k_prep<<<2048, 256, 0, stream>>>(x, WiF, WiB, WoF, WoB, Xb, WiFb, WiBb, WoFb, WoBb);
    k_inproj_mfma<<<dim3(512, 2), 256, 0, stream>>>(Xb, WiFb, WiBb, cwF, cbF, cwB, cbB,
                                                    dtbF, dtbB, Z, XBC, DTV);
    k_chunkdiag_mfma<<<dim3(NC_, B_ * NH_, 2), 256, 0, stream>>>(XBC, DTV, AlF, AlB, DpF, DpB,
                                                                 Yb, ST, CDb);
    k_scan<<<dim3(1024, 2), 256, 0, stream>>>(ST, CDb);
    k_offdiag_fused<<<dim3(NC_, B_, 2), 256, 0, stream>>>(XBC, DTV, AlF, AlB, ST, Z,
                                                          nwF, nwB, Yb);
    k_outproj_mfma<<<dim3(512), 512, 0, stream>>>(Yb, WoFb, WoBb, (float*)d_out);
}